// Round 1
// baseline (6228.665 us; speedup 1.0000x reference)
//
#include <hip/hip_runtime.h>
#include <math.h>

#define BB    2
#define NN    2048
#define CDIM  1024
#define HEADS 16
#define HDIM  64
#define MLPD  4096
#define MODC  6144
#define EPSV  1e-5f

// ---------------------------------------------------------------------------
// K1: mod = silu(t_emb) @ ada_W + ada_b        (B x 6144)
// ---------------------------------------------------------------------------
__global__ __launch_bounds__(256) void mod_kernel(
    const float* __restrict__ t_emb, const float* __restrict__ ada_W,
    const float* __restrict__ ada_b, float* __restrict__ mod) {
  int b = blockIdx.y;
  int j = blockIdx.x * 256 + threadIdx.x;
  __shared__ float st[CDIM];
  for (int i = threadIdx.x; i < CDIM; i += 256) {
    float v = t_emb[b * CDIM + i];
    st[i] = v / (1.0f + expf(-v));
  }
  __syncthreads();
  float acc = ada_b[j];
  for (int i = 0; i < CDIM; ++i) acc += st[i] * ada_W[(size_t)i * MODC + j];
  mod[b * MODC + j] = acc;
}

// ---------------------------------------------------------------------------
// K2: out = LN(x)*g+b  then  *(1+scale)+shift   (one block per row)
// ---------------------------------------------------------------------------
__device__ inline float wave_sum64(float v) {
  for (int o = 32; o > 0; o >>= 1) v += __shfl_down(v, o, 64);
  return v;
}

__global__ __launch_bounds__(256) void ln_mod_kernel(
    const float* __restrict__ x, const float* __restrict__ g,
    const float* __restrict__ bta, const float* __restrict__ mod,
    int shift_off, int scale_off, float* __restrict__ out) {
  int r = blockIdx.x;          // 0 .. B*N-1
  int b = r / NN;
  int t = threadIdx.x;
  const float* xr = x + (size_t)r * CDIM;
  float4 xv = ((const float4*)xr)[t];
  float s  = xv.x + xv.y + xv.z + xv.w;
  float s2 = xv.x*xv.x + xv.y*xv.y + xv.z*xv.z + xv.w*xv.w;
  __shared__ float ws1[4], ws2[4];
  float sw = wave_sum64(s), s2w = wave_sum64(s2);
  int lane = t & 63, wid = t >> 6;
  if (lane == 0) { ws1[wid] = sw; ws2[wid] = s2w; }
  __syncthreads();
  float s_all  = ws1[0] + ws1[1] + ws1[2] + ws1[3];
  float s2_all = ws2[0] + ws2[1] + ws2[2] + ws2[3];
  float mu  = s_all * (1.0f / CDIM);
  float var = s2_all * (1.0f / CDIM) - mu * mu;
  float rstd = rsqrtf(var + EPSV);
  const float* mods = mod + (size_t)b * MODC;
  float4 gv = ((const float4*)g)[t];
  float4 bv = ((const float4*)bta)[t];
  float4 sc = ((const float4*)(mods + scale_off))[t];
  float4 sh = ((const float4*)(mods + shift_off))[t];
  float4 o;
  o.x = ((xv.x - mu) * rstd * gv.x + bv.x) * (1.0f + sc.x) + sh.x;
  o.y = ((xv.y - mu) * rstd * gv.y + bv.y) * (1.0f + sc.y) + sh.y;
  o.z = ((xv.z - mu) * rstd * gv.z + bv.z) * (1.0f + sc.z) + sh.z;
  o.w = ((xv.w - mu) * rstd * gv.w + bv.w) * (1.0f + sc.w) + sh.w;
  ((float4*)(out + (size_t)r * CDIM))[t] = o;
}

// ---------------------------------------------------------------------------
// K3: generic fp32 tiled GEMM  C[M,Nn] = A[M,K] @ W[K,Nn]  (+ epilogue)
// mode 0: plain   mode 1: exact GELU   mode 2: res + gate*val
// 64x64 tile, K-tile 16, 256 threads, 4x4 register tile per thread
// ---------------------------------------------------------------------------
__global__ __launch_bounds__(256) void gemm_kernel(
    const float* __restrict__ A, const float* __restrict__ W,
    float* __restrict__ C, int M, int Nn, int K,
    const float* __restrict__ res, const float* __restrict__ mod,
    int gate_off, int mode) {
  __shared__ float As[16][68];   // As[kk][row]   (+4 pad: 16B-aligned rows, 2-way banks)
  __shared__ float Bs[16][64];   // Bs[kk][col]
  int tid = threadIdx.x;
  int tx = tid & 15, ty = tid >> 4;
  int brow = blockIdx.y * 64;
  int bcol = blockIdx.x * 64;
  float acc[4][4] = {};
  int akk = tid & 15;            // A staging: kk fast, rows by wave
  int bkk = tid >> 4;            // B staging
  int bc4 = (tid & 15) * 4;
  for (int k0 = 0; k0 < K; k0 += 16) {
    #pragma unroll
    for (int p = 0; p < 4; ++p) {
      int row = ty + p * 16;
      As[akk][row] = A[(size_t)(brow + row) * K + k0 + akk];
    }
    float4 bv = *((const float4*)(W + (size_t)(k0 + bkk) * Nn + bcol + bc4));
    *((float4*)&Bs[bkk][bc4]) = bv;
    __syncthreads();
    #pragma unroll
    for (int kk = 0; kk < 16; ++kk) {
      float4 a4 = *((const float4*)&As[kk][ty * 4]);
      float4 b4 = *((const float4*)&Bs[kk][tx * 4]);
      float a_[4] = {a4.x, a4.y, a4.z, a4.w};
      float b_[4] = {b4.x, b4.y, b4.z, b4.w};
      #pragma unroll
      for (int i = 0; i < 4; ++i)
        #pragma unroll
        for (int j = 0; j < 4; ++j) acc[i][j] += a_[i] * b_[j];
    }
    __syncthreads();
  }
  #pragma unroll
  for (int i = 0; i < 4; ++i) {
    size_t r = brow + ty * 4 + i;
    const float* modrow = (mode == 2) ? (mod + (r / NN) * MODC + gate_off) : nullptr;
    float tmp[4];
    #pragma unroll
    for (int j = 0; j < 4; ++j) {
      int c = bcol + tx * 4 + j;
      float v = acc[i][j];
      if (mode == 1) v = 0.5f * v * (1.0f + erff(v * 0.70710678118f));
      else if (mode == 2) v = res[r * Nn + c] + modrow[c] * v;
      tmp[j] = v;
    }
    *((float4*)&C[r * Nn + bcol + tx * 4]) =
        make_float4(tmp[0], tmp[1], tmp[2], tmp[3]);
  }
}

// ---------------------------------------------------------------------------
// K4: in-place RoPE on a (B,N,H*D) buffer. Interleaved pairing:
// rh[d] = -x[2d+1] (d<32),  x[2(d-32)] (d>=32);  freq index = d % 32.
// ---------------------------------------------------------------------------
__global__ __launch_bounds__(256) void rope_kernel(float* __restrict__ q) {
  int r = blockIdx.x;            // b*N + n
  int n = r % NN;
  int t = threadIdx.x;
  __shared__ float row[CDIM];
  float* qr = q + (size_t)r * CDIM;
  ((float4*)row)[t] = ((const float4*)qr)[t];
  __syncthreads();
  float o[4];
  #pragma unroll
  for (int q4 = 0; q4 < 4; ++q4) {
    int c = t * 4 + q4;
    int h = c >> 6, d = c & 63;
    int i = d & 31;
    float inv = powf(10000.0f, -(float)i / 32.0f);
    float ang = (float)n * inv;
    float sn, cs;
    sincosf(ang, &sn, &cs);
    float rh = (d < 32) ? -row[h * 64 + 2 * d + 1] : row[h * 64 + 2 * (d - 32)];
    o[q4] = row[c] * cs + rh * sn;
  }
  ((float4*)qr)[t] = make_float4(o[0], o[1], o[2], o[3]);
}

// ---------------------------------------------------------------------------
// K5: attention, one block per (b,h,query n). Scores in LDS, softmax, PV.
// q/k/v are in (B,N,H*D) layout; head slice is strided.
// ---------------------------------------------------------------------------
__global__ __launch_bounds__(256) void attn_kernel(
    const float* __restrict__ qt, const float* __restrict__ kt,
    const float* __restrict__ vt, float* __restrict__ attnout) {
  int n = blockIdx.x;
  int bh = blockIdx.y;
  int b = bh >> 4, h = bh & 15;
  int t = threadIdx.x;
  __shared__ float sq[HDIM];
  __shared__ float ss[NN];
  __shared__ float red[4];
  __shared__ float sacc[4][HDIM];
  const float scale = 0.125f;    // 1/sqrt(64)
  const float* qrow = qt + ((size_t)(b * NN + n) * CDIM + h * HDIM);
  if (t < 16) {
    float4 v = ((const float4*)qrow)[t];
    ((float4*)sq)[t] = make_float4(v.x * scale, v.y * scale, v.z * scale, v.w * scale);
  }
  __syncthreads();
  // scores + local max
  float lmax = -1e30f;
  for (int j = t; j < NN; j += 256) {
    const float* krow = kt + ((size_t)(b * NN + j) * CDIM + h * HDIM);
    float acc = 0.f;
    #pragma unroll
    for (int d4 = 0; d4 < 16; ++d4) {
      float4 kv = ((const float4*)krow)[d4];
      float4 qv = ((const float4*)sq)[d4];
      acc += kv.x*qv.x + kv.y*qv.y + kv.z*qv.z + kv.w*qv.w;
    }
    ss[j] = acc;
    lmax = fmaxf(lmax, acc);
  }
  for (int o = 32; o > 0; o >>= 1) lmax = fmaxf(lmax, __shfl_down(lmax, o, 64));
  if ((t & 63) == 0) red[t >> 6] = lmax;
  __syncthreads();
  float m = fmaxf(fmaxf(red[0], red[1]), fmaxf(red[2], red[3]));
  // exp + sum
  float lsum = 0.f;
  for (int j = t; j < NN; j += 256) {
    float p = __expf(ss[j] - m);
    ss[j] = p;
    lsum += p;
  }
  lsum = wave_sum64(lsum);
  __syncthreads();               // red reads done; ss writes done
  if ((t & 63) == 0) red[t >> 6] = lsum;
  __syncthreads();
  float inv = 1.0f / (red[0] + red[1] + red[2] + red[3]);
  // PV: thread (part, d) accumulates 512 keys
  int d = t & 63, part = t >> 6;
  float acc = 0.f;
  const float* vbase = vt + ((size_t)b * NN * CDIM + h * HDIM + d);
  for (int j = part * 512; j < part * 512 + 512; ++j)
    acc += ss[j] * vbase[(size_t)j * CDIM];
  sacc[part][d] = acc;
  __syncthreads();
  if (t < 64) {
    float o = (sacc[0][t] + sacc[1][t] + sacc[2][t] + sacc[3][t]) * inv;
    attnout[(size_t)(b * NN + n) * CDIM + h * HDIM + t] = o;
  }
}

// ---------------------------------------------------------------------------
extern "C" void kernel_launch(void* const* d_in, const int* in_sizes, int n_in,
                              void* d_out, int out_size, void* d_ws, size_t ws_size,
                              hipStream_t stream) {
  const float* x    = (const float*)d_in[0];
  const float* temb = (const float*)d_in[1];
  const float* n1g  = (const float*)d_in[2];
  const float* n1b  = (const float*)d_in[3];
  const float* Wq   = (const float*)d_in[4];
  const float* Wk   = (const float*)d_in[5];
  const float* Wv   = (const float*)d_in[6];
  const float* Wo   = (const float*)d_in[7];
  const float* n2g  = (const float*)d_in[8];
  const float* n2b  = (const float*)d_in[9];
  const float* W1   = (const float*)d_in[10];
  const float* W2   = (const float*)d_in[11];
  const float* adaW = (const float*)d_in[12];
  const float* adab = (const float*)d_in[13];
  float* out = (float*)d_out;

  const size_t TOK = (size_t)BB * NN * CDIM;   // 4,194,304
  float* wsf = (float*)d_ws;
  float* mod = wsf;                 // 12,288 (pad to 16,384)
  float* xn  = wsf + 16384;
  float* qt  = xn + TOK;
  float* kt  = qt + TOK;
  float* vt  = kt + TOK;
  float* h1  = vt + TOK;            // B*N*MLP = 16,777,216
  float* attnout = xn;              // reuse: xn dead after QKV
  float* x1  = qt;                  // reuse: qt dead after attention
  float* xn2 = kt;                  // reuse: kt dead after attention

  const int M = BB * NN;            // 4096 rows

  mod_kernel<<<dim3(MODC / 256, BB), 256, 0, stream>>>(temb, adaW, adab, mod);
  ln_mod_kernel<<<dim3(M), 256, 0, stream>>>(x, n1g, n1b, mod, 0, 1024, xn);

  dim3 gC(CDIM / 64, M / 64);
  gemm_kernel<<<gC, 256, 0, stream>>>(xn, Wq, qt, M, CDIM, CDIM, nullptr, nullptr, 0, 0);
  gemm_kernel<<<gC, 256, 0, stream>>>(xn, Wk, kt, M, CDIM, CDIM, nullptr, nullptr, 0, 0);
  gemm_kernel<<<gC, 256, 0, stream>>>(xn, Wv, vt, M, CDIM, CDIM, nullptr, nullptr, 0, 0);

  rope_kernel<<<dim3(M), 256, 0, stream>>>(qt);
  rope_kernel<<<dim3(M), 256, 0, stream>>>(kt);

  attn_kernel<<<dim3(NN, BB * HEADS), 256, 0, stream>>>(qt, kt, vt, attnout);

  // x1 = x + gate_msa * (attnout @ Wo)
  gemm_kernel<<<gC, 256, 0, stream>>>(attnout, Wo, x1, M, CDIM, CDIM, x, mod, 2048, 2);

  ln_mod_kernel<<<dim3(M), 256, 0, stream>>>(x1, n2g, n2b, mod, 3072, 4096, xn2);

  // h1 = gelu(xn2 @ W1)
  gemm_kernel<<<dim3(MLPD / 64, M / 64), 256, 0, stream>>>(
      xn2, W1, h1, M, MLPD, CDIM, nullptr, nullptr, 0, 1);
  // out = x1 + gate_mlp * (h1 @ W2)
  gemm_kernel<<<gC, 256, 0, stream>>>(h1, W2, out, M, CDIM, MLPD, x1, mod, 5120, 2);
}

// Round 2
// 2296.733 us; speedup vs baseline: 2.7120x; 2.7120x over previous
//
#include <hip/hip_runtime.h>
#include <math.h>

#define BB    2
#define NN    2048
#define CDIM  1024
#define HEADS 16
#define HDIM  64
#define MLPD  4096
#define MODC  6144
#define EPSV  1e-5f

// ---------------------------------------------------------------------------
// K1: mod = silu(t_emb) @ ada_W + ada_b        (B x 6144)
// ---------------------------------------------------------------------------
__global__ __launch_bounds__(256) void mod_kernel(
    const float* __restrict__ t_emb, const float* __restrict__ ada_W,
    const float* __restrict__ ada_b, float* __restrict__ mod) {
  int b = blockIdx.y;
  int j = blockIdx.x * 256 + threadIdx.x;
  __shared__ float st[CDIM];
  for (int i = threadIdx.x; i < CDIM; i += 256) {
    float v = t_emb[b * CDIM + i];
    st[i] = v / (1.0f + expf(-v));
  }
  __syncthreads();
  float acc = ada_b[j];
  for (int i = 0; i < CDIM; ++i) acc += st[i] * ada_W[(size_t)i * MODC + j];
  mod[b * MODC + j] = acc;
}

// ---------------------------------------------------------------------------
// K2: out = LN(x)*g+b  then  *(1+scale)+shift   (one block per row)
// ---------------------------------------------------------------------------
__device__ inline float wave_sum64(float v) {
  for (int o = 32; o > 0; o >>= 1) v += __shfl_down(v, o, 64);
  return v;
}

__global__ __launch_bounds__(256) void ln_mod_kernel(
    const float* __restrict__ x, const float* __restrict__ g,
    const float* __restrict__ bta, const float* __restrict__ mod,
    int shift_off, int scale_off, float* __restrict__ out) {
  int r = blockIdx.x;          // 0 .. B*N-1
  int b = r / NN;
  int t = threadIdx.x;
  const float* xr = x + (size_t)r * CDIM;
  float4 xv = ((const float4*)xr)[t];
  float s  = xv.x + xv.y + xv.z + xv.w;
  float s2 = xv.x*xv.x + xv.y*xv.y + xv.z*xv.z + xv.w*xv.w;
  __shared__ float ws1[4], ws2[4];
  float sw = wave_sum64(s), s2w = wave_sum64(s2);
  int lane = t & 63, wid = t >> 6;
  if (lane == 0) { ws1[wid] = sw; ws2[wid] = s2w; }
  __syncthreads();
  float s_all  = ws1[0] + ws1[1] + ws1[2] + ws1[3];
  float s2_all = ws2[0] + ws2[1] + ws2[2] + ws2[3];
  float mu  = s_all * (1.0f / CDIM);
  float var = s2_all * (1.0f / CDIM) - mu * mu;
  float rstd = rsqrtf(var + EPSV);
  const float* mods = mod + (size_t)b * MODC;
  float4 gv = ((const float4*)g)[t];
  float4 bv = ((const float4*)bta)[t];
  float4 sc = ((const float4*)(mods + scale_off))[t];
  float4 sh = ((const float4*)(mods + shift_off))[t];
  float4 o;
  o.x = ((xv.x - mu) * rstd * gv.x + bv.x) * (1.0f + sc.x) + sh.x;
  o.y = ((xv.y - mu) * rstd * gv.y + bv.y) * (1.0f + sc.y) + sh.y;
  o.z = ((xv.z - mu) * rstd * gv.z + bv.z) * (1.0f + sc.z) + sh.z;
  o.w = ((xv.w - mu) * rstd * gv.w + bv.w) * (1.0f + sc.w) + sh.w;
  ((float4*)(out + (size_t)r * CDIM))[t] = o;
}

// ---------------------------------------------------------------------------
// K3: generic fp32 tiled GEMM  C[M,Nn] = A[M,K] @ W[K,Nn]  (+ epilogue)
// mode 0: plain   mode 1: exact GELU   mode 2: res + gate*val
// ---------------------------------------------------------------------------
__global__ __launch_bounds__(256) void gemm_kernel(
    const float* __restrict__ A, const float* __restrict__ W,
    float* __restrict__ C, int M, int Nn, int K,
    const float* __restrict__ res, const float* __restrict__ mod,
    int gate_off, int mode) {
  __shared__ float As[16][68];
  __shared__ float Bs[16][64];
  int tid = threadIdx.x;
  int tx = tid & 15, ty = tid >> 4;
  int brow = blockIdx.y * 64;
  int bcol = blockIdx.x * 64;
  float acc[4][4] = {};
  int akk = tid & 15;
  int bkk = tid >> 4;
  int bc4 = (tid & 15) * 4;
  for (int k0 = 0; k0 < K; k0 += 16) {
    #pragma unroll
    for (int p = 0; p < 4; ++p) {
      int row = ty + p * 16;
      As[akk][row] = A[(size_t)(brow + row) * K + k0 + akk];
    }
    float4 bv = *((const float4*)(W + (size_t)(k0 + bkk) * Nn + bcol + bc4));
    *((float4*)&Bs[bkk][bc4]) = bv;
    __syncthreads();
    #pragma unroll
    for (int kk = 0; kk < 16; ++kk) {
      float4 a4 = *((const float4*)&As[kk][ty * 4]);
      float4 b4 = *((const float4*)&Bs[kk][tx * 4]);
      float a_[4] = {a4.x, a4.y, a4.z, a4.w};
      float b_[4] = {b4.x, b4.y, b4.z, b4.w};
      #pragma unroll
      for (int i = 0; i < 4; ++i)
        #pragma unroll
        for (int j = 0; j < 4; ++j) acc[i][j] += a_[i] * b_[j];
    }
    __syncthreads();
  }
  #pragma unroll
  for (int i = 0; i < 4; ++i) {
    size_t r = brow + ty * 4 + i;
    const float* modrow = (mode == 2) ? (mod + (r / NN) * MODC + gate_off) : nullptr;
    float tmp[4];
    #pragma unroll
    for (int j = 0; j < 4; ++j) {
      int c = bcol + tx * 4 + j;
      float v = acc[i][j];
      if (mode == 1) v = 0.5f * v * (1.0f + erff(v * 0.70710678118f));
      else if (mode == 2) v = res[r * Nn + c] + modrow[c] * v;
      tmp[j] = v;
    }
    *((float4*)&C[r * Nn + bcol + tx * 4]) =
        make_float4(tmp[0], tmp[1], tmp[2], tmp[3]);
  }
}

// ---------------------------------------------------------------------------
// K4: in-place RoPE on a (B,N,H*D) buffer (interleaved pairing).
// ---------------------------------------------------------------------------
__global__ __launch_bounds__(256) void rope_kernel(float* __restrict__ q) {
  int r = blockIdx.x;            // b*N + n
  int n = r % NN;
  int t = threadIdx.x;
  __shared__ float row[CDIM];
  float* qr = q + (size_t)r * CDIM;
  ((float4*)row)[t] = ((const float4*)qr)[t];
  __syncthreads();
  float o[4];
  #pragma unroll
  for (int q4 = 0; q4 < 4; ++q4) {
    int c = t * 4 + q4;
    int h = c >> 6, d = c & 63;
    int i = d & 31;
    float inv = powf(10000.0f, -(float)i / 32.0f);
    float ang = (float)n * inv;
    float sn, cs;
    sincosf(ang, &sn, &cs);
    float rh = (d < 32) ? -row[h * 64 + 2 * d + 1] : row[h * 64 + 2 * (d - 32)];
    o[q4] = row[c] * cs + rh * sn;
  }
  ((float4*)qr)[t] = make_float4(o[0], o[1], o[2], o[3]);
}

// ---------------------------------------------------------------------------
// K5: flash-style tiled attention.
// Grid: (N/64, B*H). Block: 256 threads = 16x16; each thread owns a 4x4
// micro-tile. LDS: Qt (Q^T, scaled), KP (K^T during S; P^T during PV), Vs.
// Online softmax per q-row; row group = 16 lanes (same ty) -> shfl_xor.
// ---------------------------------------------------------------------------
__global__ __launch_bounds__(256) void fattn_kernel(
    const float* __restrict__ qt, const float* __restrict__ kt,
    const float* __restrict__ vt, float* __restrict__ attnout) {
  int qtile = blockIdx.x;
  int bh = blockIdx.y;
  int b = bh >> 4, h = bh & 15;
  int tid = threadIdx.x;
  int tx = tid & 15, ty = tid >> 4;

  __shared__ float Qt[64][72];   // Qt[d][qi]
  __shared__ float KP[64][72];   // Kt[d][kj] during S; Pt[kj][qi] during PV
  __shared__ float Vs[64][72];   // Vs[kj][d]

  const float scale = 0.125f;    // 1/sqrt(64)
  int n0 = qtile * 64;
  const float* qbase = qt + ((size_t)(b * NN + n0) * CDIM + h * HDIM);
  for (int idx = tid; idx < 64 * 64; idx += 256) {
    int qi = idx >> 6, d = idx & 63;       // d fast -> coalesced global read
    Qt[d][qi] = qbase[(size_t)qi * CDIM + d] * scale;
  }

  float acc[4][4] = {};
  float m_i[4] = {-1e30f, -1e30f, -1e30f, -1e30f};
  float l_i[4] = {0.f, 0.f, 0.f, 0.f};

  for (int k0 = 0; k0 < NN; k0 += 64) {
    __syncthreads();   // prev iter's PV reads of KP/Vs complete
    const float* kbase = kt + ((size_t)(b * NN + k0) * CDIM + h * HDIM);
    const float* vbase = vt + ((size_t)(b * NN + k0) * CDIM + h * HDIM);
    for (int idx = tid; idx < 64 * 64; idx += 256) {
      int kj = idx >> 6, d = idx & 63;
      KP[d][kj] = kbase[(size_t)kj * CDIM + d];     // transpose K
    }
    for (int idx = tid; idx < 64 * 64; idx += 256) {
      int kj = idx >> 6, d = idx & 63;
      Vs[kj][d] = vbase[(size_t)kj * CDIM + d];     // V straight
    }
    __syncthreads();

    // ---- S = Q K^T ----  s[i][j]: row n0+ty*4+i, col k0+tx*4+j
    float s[4][4] = {};
    #pragma unroll 8
    for (int kk = 0; kk < 64; ++kk) {
      float4 a4 = *((const float4*)&Qt[kk][ty * 4]);
      float4 b4 = *((const float4*)&KP[kk][tx * 4]);
      float a_[4] = {a4.x, a4.y, a4.z, a4.w};
      float b_[4] = {b4.x, b4.y, b4.z, b4.w};
      #pragma unroll
      for (int i = 0; i < 4; ++i)
        #pragma unroll
        for (int j = 0; j < 4; ++j) s[i][j] += a_[i] * b_[j];
    }

    // ---- online softmax (registers + shfl over the 16-lane row group) ----
    float mloc[4], lsum[4], alpha[4];
    #pragma unroll
    for (int i = 0; i < 4; ++i) {
      float mv = fmaxf(fmaxf(s[i][0], s[i][1]), fmaxf(s[i][2], s[i][3]));
      #pragma unroll
      for (int msk = 1; msk < 16; msk <<= 1)
        mv = fmaxf(mv, __shfl_xor(mv, msk, 64));
      float mnew = fmaxf(m_i[i], mv);
      alpha[i] = __expf(m_i[i] - mnew);
      m_i[i] = mnew;
      float ls = 0.f;
      #pragma unroll
      for (int j = 0; j < 4; ++j) {
        s[i][j] = __expf(s[i][j] - mnew);
        ls += s[i][j];
      }
      #pragma unroll
      for (int msk = 1; msk < 16; msk <<= 1)
        ls += __shfl_xor(ls, msk, 64);
      lsum[i] = ls;
    }
    #pragma unroll
    for (int i = 0; i < 4; ++i) {
      l_i[i] = l_i[i] * alpha[i] + lsum[i];
      #pragma unroll
      for (int j = 0; j < 4; ++j) acc[i][j] *= alpha[i];
    }

    __syncthreads();   // all S reads of KP (as K^T) complete
    // write P^T into KP: Pt[kj][qi]
    #pragma unroll
    for (int j = 0; j < 4; ++j)
      #pragma unroll
      for (int i = 0; i < 4; ++i)
        KP[tx * 4 + j][ty * 4 + i] = s[i][j];
    __syncthreads();

    // ---- acc += P V ----  acc[i][j]: row n0+ty*4+i, dim tx*4+j
    #pragma unroll 8
    for (int kk = 0; kk < 64; ++kk) {
      float4 a4 = *((const float4*)&KP[kk][ty * 4]);
      float4 b4 = *((const float4*)&Vs[kk][tx * 4]);
      float a_[4] = {a4.x, a4.y, a4.z, a4.w};
      float b_[4] = {b4.x, b4.y, b4.z, b4.w};
      #pragma unroll
      for (int i = 0; i < 4; ++i)
        #pragma unroll
        for (int j = 0; j < 4; ++j) acc[i][j] += a_[i] * b_[j];
    }
  }

  // ---- epilogue: normalize and store ----
  #pragma unroll
  for (int i = 0; i < 4; ++i) {
    float inv = 1.0f / l_i[i];
    size_t row = (size_t)(b * NN + n0 + ty * 4 + i);
    *((float4*)&attnout[row * CDIM + h * HDIM + tx * 4]) =
        make_float4(acc[i][0] * inv, acc[i][1] * inv,
                    acc[i][2] * inv, acc[i][3] * inv);
  }
}

// ---------------------------------------------------------------------------
extern "C" void kernel_launch(void* const* d_in, const int* in_sizes, int n_in,
                              void* d_out, int out_size, void* d_ws, size_t ws_size,
                              hipStream_t stream) {
  const float* x    = (const float*)d_in[0];
  const float* temb = (const float*)d_in[1];
  const float* n1g  = (const float*)d_in[2];
  const float* n1b  = (const float*)d_in[3];
  const float* Wq   = (const float*)d_in[4];
  const float* Wk   = (const float*)d_in[5];
  const float* Wv   = (const float*)d_in[6];
  const float* Wo   = (const float*)d_in[7];
  const float* n2g  = (const float*)d_in[8];
  const float* n2b  = (const float*)d_in[9];
  const float* W1   = (const float*)d_in[10];
  const float* W2   = (const float*)d_in[11];
  const float* adaW = (const float*)d_in[12];
  const float* adab = (const float*)d_in[13];
  float* out = (float*)d_out;

  const size_t TOK = (size_t)BB * NN * CDIM;
  float* wsf = (float*)d_ws;
  float* mod = wsf;
  float* xn  = wsf + 16384;
  float* qt  = xn + TOK;
  float* kt  = qt + TOK;
  float* vt  = kt + TOK;
  float* h1  = vt + TOK;
  float* attnout = xn;
  float* x1  = qt;
  float* xn2 = kt;

  const int M = BB * NN;

  mod_kernel<<<dim3(MODC / 256, BB), 256, 0, stream>>>(temb, adaW, adab, mod);
  ln_mod_kernel<<<dim3(M), 256, 0, stream>>>(x, n1g, n1b, mod, 0, 1024, xn);

  dim3 gC(CDIM / 64, M / 64);
  gemm_kernel<<<gC, 256, 0, stream>>>(xn, Wq, qt, M, CDIM, CDIM, nullptr, nullptr, 0, 0);
  gemm_kernel<<<gC, 256, 0, stream>>>(xn, Wk, kt, M, CDIM, CDIM, nullptr, nullptr, 0, 0);
  gemm_kernel<<<gC, 256, 0, stream>>>(xn, Wv, vt, M, CDIM, CDIM, nullptr, nullptr, 0, 0);

  rope_kernel<<<dim3(M), 256, 0, stream>>>(qt);
  rope_kernel<<<dim3(M), 256, 0, stream>>>(kt);

  fattn_kernel<<<dim3(NN / 64, BB * HEADS), 256, 0, stream>>>(qt, kt, vt, attnout);

  gemm_kernel<<<gC, 256, 0, stream>>>(attnout, Wo, x1, M, CDIM, CDIM, x, mod, 2048, 2);

  ln_mod_kernel<<<dim3(M), 256, 0, stream>>>(x1, n2g, n2b, mod, 3072, 4096, xn2);

  gemm_kernel<<<dim3(MLPD / 64, M / 64), 256, 0, stream>>>(
      xn2, W1, h1, M, MLPD, CDIM, nullptr, nullptr, 0, 1);
  gemm_kernel<<<gC, 256, 0, stream>>>(h1, W2, out, M, CDIM, MLPD, x1, mod, 5120, 2);
}

// Round 3
// 1242.366 us; speedup vs baseline: 5.0136x; 1.8487x over previous
//
#include <hip/hip_runtime.h>
#include <math.h>

#define BB    2
#define NN    2048
#define CDIM  1024
#define HEADS 16
#define HDIM  64
#define MLPD  4096
#define MODC  6144
#define EPSV  1e-5f

typedef __attribute__((ext_vector_type(8))) short s8v;     // 8 bf16 (4 VGPRs)
typedef __attribute__((ext_vector_type(4))) float f4v;     // MFMA C/D

__device__ inline unsigned short f2bf(float f) {
  union { float f; unsigned u; } v; v.f = f;
  unsigned r = v.u + 0x7FFFu + ((v.u >> 16) & 1u);   // RNE
  return (unsigned short)(r >> 16);
}

// ---------------------------------------------------------------------------
// K1: mod = silu(t_emb) @ ada_W + ada_b        (B x 6144)
// ---------------------------------------------------------------------------
__global__ __launch_bounds__(256) void mod_kernel(
    const float* __restrict__ t_emb, const float* __restrict__ ada_W,
    const float* __restrict__ ada_b, float* __restrict__ mod) {
  int b = blockIdx.y;
  int j = blockIdx.x * 256 + threadIdx.x;
  __shared__ float st[CDIM];
  for (int i = threadIdx.x; i < CDIM; i += 256) {
    float v = t_emb[b * CDIM + i];
    st[i] = v / (1.0f + expf(-v));
  }
  __syncthreads();
  float acc = ada_b[j];
  for (int i = 0; i < CDIM; ++i) acc += st[i] * ada_W[(size_t)i * MODC + j];
  mod[b * MODC + j] = acc;
}

// ---------------------------------------------------------------------------
// K2: LN + adaLN modulation, bf16 output (feeds MFMA GEMMs)
// ---------------------------------------------------------------------------
__device__ inline float wave_sum64(float v) {
  for (int o = 32; o > 0; o >>= 1) v += __shfl_down(v, o, 64);
  return v;
}

__global__ __launch_bounds__(256) void ln_mod_bf16(
    const float* __restrict__ x, const float* __restrict__ g,
    const float* __restrict__ bta, const float* __restrict__ mod,
    int shift_off, int scale_off, unsigned short* __restrict__ out) {
  int r = blockIdx.x;
  int b = r / NN;
  int t = threadIdx.x;
  const float* xr = x + (size_t)r * CDIM;
  float4 xv = ((const float4*)xr)[t];
  float s  = xv.x + xv.y + xv.z + xv.w;
  float s2 = xv.x*xv.x + xv.y*xv.y + xv.z*xv.z + xv.w*xv.w;
  __shared__ float ws1[4], ws2[4];
  float sw = wave_sum64(s), s2w = wave_sum64(s2);
  int lane = t & 63, wid = t >> 6;
  if (lane == 0) { ws1[wid] = sw; ws2[wid] = s2w; }
  __syncthreads();
  float mu  = (ws1[0] + ws1[1] + ws1[2] + ws1[3]) * (1.0f / CDIM);
  float var = (ws2[0] + ws2[1] + ws2[2] + ws2[3]) * (1.0f / CDIM) - mu * mu;
  float rstd = rsqrtf(var + EPSV);
  const float* mods = mod + (size_t)b * MODC;
  float4 gv = ((const float4*)g)[t];
  float4 bv = ((const float4*)bta)[t];
  float4 sc = ((const float4*)(mods + scale_off))[t];
  float4 sh = ((const float4*)(mods + shift_off))[t];
  ushort4 ov;
  ov.x = f2bf(((xv.x - mu) * rstd * gv.x + bv.x) * (1.0f + sc.x) + sh.x);
  ov.y = f2bf(((xv.y - mu) * rstd * gv.y + bv.y) * (1.0f + sc.y) + sh.y);
  ov.z = f2bf(((xv.z - mu) * rstd * gv.z + bv.z) * (1.0f + sc.z) + sh.z);
  ov.w = f2bf(((xv.w - mu) * rstd * gv.w + bv.w) * (1.0f + sc.w) + sh.w);
  ((ushort4*)(out + (size_t)r * CDIM))[t] = ov;
}

// ---------------------------------------------------------------------------
// K3: transpose-cast  W[K][N] fp32  ->  Wt[N][K] bf16   (32x32 tiles)
// ---------------------------------------------------------------------------
__global__ __launch_bounds__(256) void wcast_t(
    const float* __restrict__ W, unsigned short* __restrict__ Wt,
    int K, int N) {
  __shared__ float tile[32][33];
  int tx = threadIdx.x & 31, ty = threadIdx.x >> 5;   // 32 x 8
  int n0 = blockIdx.x * 32, k0 = blockIdx.y * 32;
  #pragma unroll
  for (int p = 0; p < 4; ++p)
    tile[ty + p * 8][tx] = W[(size_t)(k0 + ty + p * 8) * N + n0 + tx];
  __syncthreads();
  #pragma unroll
  for (int p = 0; p < 4; ++p)
    Wt[(size_t)(n0 + ty + p * 8) * K + k0 + tx] = f2bf(tile[tx][ty + p * 8]);
}

// ---------------------------------------------------------------------------
// K4: bf16 MFMA GEMM (m97 structure).  C = A[M,K] @ W[K,N], Bt = W^T [N][K].
// 128x128 tile, BK=32, 4 waves (2x2), each 4x4 tiles of mfma 16x16x32.
// global_load_lds width=16, wave-uniform LDS base (no padding).
// mode 0: split fp32 out to O0/O1/O2 (qkv, each N=1024)
// mode 1: exact GELU -> bf16 Ob
// mode 2: O0 = res + mod[gate] * acc (fp32)
// ---------------------------------------------------------------------------
__global__ __launch_bounds__(256) void mfma_gemm(
    const unsigned short* __restrict__ A,   // [M][K] bf16
    const unsigned short* __restrict__ Bt,  // [N][K] bf16
    int M, int N, int K,
    float* __restrict__ O0, float* __restrict__ O1, float* __restrict__ O2,
    unsigned short* __restrict__ Ob,
    const float* __restrict__ res, const float* __restrict__ mod,
    int gate_off, int mode) {
  __shared__ unsigned short As[128 * 32];   // row-major, 64 B/row
  __shared__ unsigned short Bs[128 * 32];
  int tid = threadIdx.x;
  int wave = tid >> 6, lane = tid & 63;
  int quad = lane >> 4, l15 = lane & 15;
  int m0 = blockIdx.y * 128, n0 = blockIdx.x * 128;
  int wm = (wave >> 1) * 64, wn = (wave & 1) * 64;

  f4v acc[4][4] = {};

  // staging: instruction i covers rows 16i..16i+15 of the tile (1024 B);
  // lane l sources row l>>2, cols (l&3)*8..+8 -> matches HW lane*16 layout.
  int srow = lane >> 2;
  int scol = (lane & 3) * 8;

  for (int k0 = 0; k0 < K; k0 += 32) {
    __syncthreads();
    #pragma unroll
    for (int s = 0; s < 2; ++s) {
      int inst = 2 * wave + s;
      const unsigned short* ga =
          A + (size_t)(m0 + inst * 16 + srow) * K + k0 + scol;
      __builtin_amdgcn_global_load_lds(
          (const __attribute__((address_space(1))) unsigned int*)(const void*)ga,
          (__attribute__((address_space(3))) unsigned int*)(void*)(As + inst * 512),
          16, 0, 0);
      const unsigned short* gb =
          Bt + (size_t)(n0 + inst * 16 + srow) * K + k0 + scol;
      __builtin_amdgcn_global_load_lds(
          (const __attribute__((address_space(1))) unsigned int*)(const void*)gb,
          (__attribute__((address_space(3))) unsigned int*)(void*)(Bs + inst * 512),
          16, 0, 0);
    }
    __syncthreads();

    s8v af[4], bf[4];
    #pragma unroll
    for (int i = 0; i < 4; ++i)
      af[i] = *(const s8v*)(As + ((wm + i * 16 + l15) * 32 + quad * 8));
    #pragma unroll
    for (int j = 0; j < 4; ++j)
      bf[j] = *(const s8v*)(Bs + ((wn + j * 16 + l15) * 32 + quad * 8));
    #pragma unroll
    for (int i = 0; i < 4; ++i)
      #pragma unroll
      for (int j = 0; j < 4; ++j)
        acc[i][j] = __builtin_amdgcn_mfma_f32_16x16x32_bf16(
            af[i], bf[j], acc[i][j], 0, 0, 0);
  }

  // epilogue. C/D layout: col = lane&15, row = quad*4 + reg  [m89/m91]
  #pragma unroll
  for (int i = 0; i < 4; ++i) {
    int rbase = m0 + wm + i * 16 + quad * 4;
    #pragma unroll
    for (int j = 0; j < 4; ++j) {
      int c = n0 + wn + j * 16 + l15;
      #pragma unroll
      for (int rg = 0; rg < 4; ++rg) {
        int r = rbase + rg;
        float v = acc[i][j][rg];
        if (mode == 0) {
          int buf = c >> 10, cc = c & 1023;
          float* dst = (buf == 0) ? O0 : ((buf == 1) ? O1 : O2);
          dst[(size_t)r * 1024 + cc] = v;
        } else if (mode == 1) {
          v = 0.5f * v * (1.0f + erff(v * 0.70710678118f));
          Ob[(size_t)r * N + c] = f2bf(v);
        } else {
          int bb = r >> 11;   // NN = 2048
          v = res[(size_t)r * N + c] + mod[bb * MODC + gate_off + c] * v;
          O0[(size_t)r * N + c] = v;
        }
      }
    }
  }
}

// ---------------------------------------------------------------------------
// K5: in-place RoPE (interleaved pairing), per-block cos/sin table.
// ---------------------------------------------------------------------------
__global__ __launch_bounds__(256) void rope_kernel(float* __restrict__ q) {
  int r = blockIdx.x;            // b*N + n
  int n = r % NN;
  int t = threadIdx.x;
  __shared__ float row[CDIM];
  __shared__ float csv[32], snv[32];
  if (t < 32) {
    float invf = powf(10000.0f, -(float)t / 32.0f);
    float sn, cs;
    sincosf((float)n * invf, &sn, &cs);
    csv[t] = cs; snv[t] = sn;
  }
  float* qr = q + (size_t)r * CDIM;
  ((float4*)row)[t] = ((const float4*)qr)[t];
  __syncthreads();
  float o[4];
  #pragma unroll
  for (int q4 = 0; q4 < 4; ++q4) {
    int c = t * 4 + q4;
    int h = c >> 6, d = c & 63;
    int i = d & 31;
    float rh = (d < 32) ? -row[h * 64 + 2 * d + 1] : row[h * 64 + 2 * (d - 32)];
    o[q4] = row[c] * csv[i] + rh * snv[i];
  }
  ((float4*)qr)[t] = make_float4(o[0], o[1], o[2], o[3]);
}

// ---------------------------------------------------------------------------
// K6: flash attention (fp32 compute, bf16 output)
// ---------------------------------------------------------------------------
__global__ __launch_bounds__(256) void fattn_kernel(
    const float* __restrict__ qt, const float* __restrict__ kt,
    const float* __restrict__ vt, unsigned short* __restrict__ attnout) {
  int qtile = blockIdx.x;
  int bh = blockIdx.y;
  int b = bh >> 4, h = bh & 15;
  int tid = threadIdx.x;
  int tx = tid & 15, ty = tid >> 4;

  __shared__ float Qt[64][72];
  __shared__ float KP[64][72];
  __shared__ float Vs[64][72];

  const float scale = 0.125f;
  int n0 = qtile * 64;
  const float* qbase = qt + ((size_t)(b * NN + n0) * CDIM + h * HDIM);
  for (int idx = tid; idx < 64 * 64; idx += 256) {
    int qi = idx >> 6, d = idx & 63;
    Qt[d][qi] = qbase[(size_t)qi * CDIM + d] * scale;
  }

  float acc[4][4] = {};
  float m_i[4] = {-1e30f, -1e30f, -1e30f, -1e30f};
  float l_i[4] = {0.f, 0.f, 0.f, 0.f};

  for (int k0 = 0; k0 < NN; k0 += 64) {
    __syncthreads();
    const float* kbase = kt + ((size_t)(b * NN + k0) * CDIM + h * HDIM);
    const float* vbase = vt + ((size_t)(b * NN + k0) * CDIM + h * HDIM);
    for (int idx = tid; idx < 64 * 64; idx += 256) {
      int kj = idx >> 6, d = idx & 63;
      KP[d][kj] = kbase[(size_t)kj * CDIM + d];
    }
    for (int idx = tid; idx < 64 * 64; idx += 256) {
      int kj = idx >> 6, d = idx & 63;
      Vs[kj][d] = vbase[(size_t)kj * CDIM + d];
    }
    __syncthreads();

    float s[4][4] = {};
    #pragma unroll 8
    for (int kk = 0; kk < 64; ++kk) {
      float4 a4 = *((const float4*)&Qt[kk][ty * 4]);
      float4 b4 = *((const float4*)&KP[kk][tx * 4]);
      float a_[4] = {a4.x, a4.y, a4.z, a4.w};
      float b_[4] = {b4.x, b4.y, b4.z, b4.w};
      #pragma unroll
      for (int i = 0; i < 4; ++i)
        #pragma unroll
        for (int j = 0; j < 4; ++j) s[i][j] += a_[i] * b_[j];
    }

    float lsum[4], alpha[4];
    #pragma unroll
    for (int i = 0; i < 4; ++i) {
      float mv = fmaxf(fmaxf(s[i][0], s[i][1]), fmaxf(s[i][2], s[i][3]));
      #pragma unroll
      for (int msk = 1; msk < 16; msk <<= 1)
        mv = fmaxf(mv, __shfl_xor(mv, msk, 64));
      float mnew = fmaxf(m_i[i], mv);
      alpha[i] = __expf(m_i[i] - mnew);
      m_i[i] = mnew;
      float ls = 0.f;
      #pragma unroll
      for (int j = 0; j < 4; ++j) {
        s[i][j] = __expf(s[i][j] - mnew);
        ls += s[i][j];
      }
      #pragma unroll
      for (int msk = 1; msk < 16; msk <<= 1)
        ls += __shfl_xor(ls, msk, 64);
      lsum[i] = ls;
    }
    #pragma unroll
    for (int i = 0; i < 4; ++i) {
      l_i[i] = l_i[i] * alpha[i] + lsum[i];
      #pragma unroll
      for (int j = 0; j < 4; ++j) acc[i][j] *= alpha[i];
    }

    __syncthreads();
    #pragma unroll
    for (int j = 0; j < 4; ++j)
      #pragma unroll
      for (int i = 0; i < 4; ++i)
        KP[tx * 4 + j][ty * 4 + i] = s[i][j];
    __syncthreads();

    #pragma unroll 8
    for (int kk = 0; kk < 64; ++kk) {
      float4 a4 = *((const float4*)&KP[kk][ty * 4]);
      float4 b4 = *((const float4*)&Vs[kk][tx * 4]);
      float a_[4] = {a4.x, a4.y, a4.z, a4.w};
      float b_[4] = {b4.x, b4.y, b4.z, b4.w};
      #pragma unroll
      for (int i = 0; i < 4; ++i)
        #pragma unroll
        for (int j = 0; j < 4; ++j) acc[i][j] += a_[i] * b_[j];
    }
  }

  #pragma unroll
  for (int i = 0; i < 4; ++i) {
    float inv = 1.0f / l_i[i];
    size_t row = (size_t)(b * NN + n0 + ty * 4 + i);
    ushort4 st = make_ushort4(f2bf(acc[i][0] * inv), f2bf(acc[i][1] * inv),
                              f2bf(acc[i][2] * inv), f2bf(acc[i][3] * inv));
    *((ushort4*)&attnout[row * CDIM + h * HDIM + tx * 4]) = st;
  }
}

// ---------------------------------------------------------------------------
extern "C" void kernel_launch(void* const* d_in, const int* in_sizes, int n_in,
                              void* d_out, int out_size, void* d_ws, size_t ws_size,
                              hipStream_t stream) {
  const float* x    = (const float*)d_in[0];
  const float* temb = (const float*)d_in[1];
  const float* n1g  = (const float*)d_in[2];
  const float* n1b  = (const float*)d_in[3];
  const float* Wq   = (const float*)d_in[4];
  const float* Wk   = (const float*)d_in[5];
  const float* Wv   = (const float*)d_in[6];
  const float* Wo   = (const float*)d_in[7];
  const float* n2g  = (const float*)d_in[8];
  const float* n2b  = (const float*)d_in[9];
  const float* W1   = (const float*)d_in[10];
  const float* W2   = (const float*)d_in[11];
  const float* adaW = (const float*)d_in[12];
  const float* adab = (const float*)d_in[13];
  float* out = (float*)d_out;

  const size_t TOK = (size_t)BB * NN * CDIM;   // 4,194,304 tokensxdim
  float* wsf = (float*)d_ws;
  // layout (f32 units). Sequential-lifetime buffers share regions:
  float* mod = wsf;                                   // 16384
  unsigned short* tokb = (unsigned short*)(wsf + 16384);   // TOK bf16 (xn/attn/xn2)
  float* qt = wsf + 16384 + TOK / 2;                  // TOK f32 (later x1)
  float* kt = qt + TOK;                               // TOK f32 \ later h1b
  float* vt = kt + TOK;                               // TOK f32 / (2*TOK bf16)
  unsigned short* Wqkvt = (unsigned short*)(vt + TOK);     // 3M bf16
  unsigned short* Wot   = Wqkvt + 3 * CDIM * CDIM;         // 1M bf16
  unsigned short* W1t   = Wot + CDIM * CDIM;               // 4M bf16
  unsigned short* W2t   = W1t + CDIM * MLPD;               // 4M bf16
  float* x1 = qt;
  unsigned short* h1b = (unsigned short*)kt;

  const int M = BB * NN;   // 4096

  mod_kernel<<<dim3(MODC / 256, BB), 256, 0, stream>>>(temb, adaW, adab, mod);
  ln_mod_bf16<<<dim3(M), 256, 0, stream>>>(x, n1g, n1b, mod, 0, 1024, tokb);

  // weight transpose-casts
  wcast_t<<<dim3(32, 32), 256, 0, stream>>>(Wq, Wqkvt, CDIM, CDIM);
  wcast_t<<<dim3(32, 32), 256, 0, stream>>>(Wk, Wqkvt + CDIM * CDIM, CDIM, CDIM);
  wcast_t<<<dim3(32, 32), 256, 0, stream>>>(Wv, Wqkvt + 2 * CDIM * CDIM, CDIM, CDIM);
  wcast_t<<<dim3(32, 32), 256, 0, stream>>>(Wo, Wot, CDIM, CDIM);
  wcast_t<<<dim3(128, 32), 256, 0, stream>>>(W1, W1t, CDIM, MLPD);
  wcast_t<<<dim3(32, 128), 256, 0, stream>>>(W2, W2t, MLPD, CDIM);

  // fused QKV: [4096,1024] @ [1024,3072] -> qt|kt|vt
  mfma_gemm<<<dim3(24, 32), 256, 0, stream>>>(
      tokb, Wqkvt, M, 3 * CDIM, CDIM, qt, kt, vt, nullptr, nullptr, nullptr, 0, 0);

  rope_kernel<<<dim3(M), 256, 0, stream>>>(qt);
  rope_kernel<<<dim3(M), 256, 0, stream>>>(kt);

  fattn_kernel<<<dim3(NN / 64, BB * HEADS), 256, 0, stream>>>(qt, kt, vt, tokb);

  // x1 = x + gate_msa * (attn @ Wo)
  mfma_gemm<<<dim3(8, 32), 256, 0, stream>>>(
      tokb, Wot, M, CDIM, CDIM, x1, nullptr, nullptr, nullptr, x, mod, 2048, 2);

  ln_mod_bf16<<<dim3(M), 256, 0, stream>>>(x1, n2g, n2b, mod, 3072, 4096, tokb);

  // h1 = gelu(xn2 @ W1)  (bf16 out)
  mfma_gemm<<<dim3(32, 32), 256, 0, stream>>>(
      tokb, W1t, M, MLPD, CDIM, nullptr, nullptr, nullptr, h1b, nullptr, nullptr, 0, 1);

  // out = x1 + gate_mlp * (h1 @ W2)
  mfma_gemm<<<dim3(8, 32), 256, 0, stream>>>(
      h1b, W2t, M, CDIM, MLPD, out, nullptr, nullptr, nullptr, x1, mod, 5120, 2);
}

// Round 4
// 608.475 us; speedup vs baseline: 10.2365x; 2.0418x over previous
//
#include <hip/hip_runtime.h>
#include <math.h>

#define BB    2
#define NN    2048
#define CDIM  1024
#define HEADS 16
#define HDIM  64
#define MLPD  4096
#define MODC  6144
#define EPSV  1e-5f

typedef __attribute__((ext_vector_type(8))) short s8v;     // 8 bf16 (4 VGPRs)
typedef __attribute__((ext_vector_type(4))) float f4v;     // MFMA C/D

__device__ inline unsigned short f2bf(float f) {
  union { float f; unsigned u; } v; v.f = f;
  unsigned r = v.u + 0x7FFFu + ((v.u >> 16) & 1u);   // RNE
  return (unsigned short)(r >> 16);
}
__device__ inline float bf2f(unsigned short h) {
  union { unsigned u; float f; } v; v.u = ((unsigned)h) << 16;
  return v.f;
}

// ---------------------------------------------------------------------------
// K1: mod = silu(t_emb) @ ada_W + ada_b        (B x 6144)
// ---------------------------------------------------------------------------
__global__ __launch_bounds__(256) void mod_kernel(
    const float* __restrict__ t_emb, const float* __restrict__ ada_W,
    const float* __restrict__ ada_b, float* __restrict__ mod) {
  int b = blockIdx.y;
  int j = blockIdx.x * 256 + threadIdx.x;
  __shared__ float st[CDIM];
  for (int i = threadIdx.x; i < CDIM; i += 256) {
    float v = t_emb[b * CDIM + i];
    st[i] = v / (1.0f + expf(-v));
  }
  __syncthreads();
  float acc = ada_b[j];
  for (int i = 0; i < CDIM; ++i) acc += st[i] * ada_W[(size_t)i * MODC + j];
  mod[b * MODC + j] = acc;
}

// ---------------------------------------------------------------------------
// K2: LN + adaLN modulation, bf16 output
// ---------------------------------------------------------------------------
__device__ inline float wave_sum64(float v) {
  for (int o = 32; o > 0; o >>= 1) v += __shfl_down(v, o, 64);
  return v;
}

__global__ __launch_bounds__(256) void ln_mod_bf16(
    const float* __restrict__ x, const float* __restrict__ g,
    const float* __restrict__ bta, const float* __restrict__ mod,
    int shift_off, int scale_off, unsigned short* __restrict__ out) {
  int r = blockIdx.x;
  int b = r / NN;
  int t = threadIdx.x;
  const float* xr = x + (size_t)r * CDIM;
  float4 xv = ((const float4*)xr)[t];
  float s  = xv.x + xv.y + xv.z + xv.w;
  float s2 = xv.x*xv.x + xv.y*xv.y + xv.z*xv.z + xv.w*xv.w;
  __shared__ float ws1[4], ws2[4];
  float sw = wave_sum64(s), s2w = wave_sum64(s2);
  int lane = t & 63, wid = t >> 6;
  if (lane == 0) { ws1[wid] = sw; ws2[wid] = s2w; }
  __syncthreads();
  float mu  = (ws1[0] + ws1[1] + ws1[2] + ws1[3]) * (1.0f / CDIM);
  float var = (ws2[0] + ws2[1] + ws2[2] + ws2[3]) * (1.0f / CDIM) - mu * mu;
  float rstd = rsqrtf(var + EPSV);
  const float* mods = mod + (size_t)b * MODC;
  float4 gv = ((const float4*)g)[t];
  float4 bv = ((const float4*)bta)[t];
  float4 sc = ((const float4*)(mods + scale_off))[t];
  float4 sh = ((const float4*)(mods + shift_off))[t];
  ushort4 ov;
  ov.x = f2bf(((xv.x - mu) * rstd * gv.x + bv.x) * (1.0f + sc.x) + sh.x);
  ov.y = f2bf(((xv.y - mu) * rstd * gv.y + bv.y) * (1.0f + sc.y) + sh.y);
  ov.z = f2bf(((xv.z - mu) * rstd * gv.z + bv.z) * (1.0f + sc.z) + sh.z);
  ov.w = f2bf(((xv.w - mu) * rstd * gv.w + bv.w) * (1.0f + sc.w) + sh.w);
  ((ushort4*)(out + (size_t)r * CDIM))[t] = ov;
}

// ---------------------------------------------------------------------------
// K3: transpose-cast  W[K][N] fp32  ->  Wt[N][K] bf16   (32x32 tiles)
// ---------------------------------------------------------------------------
__global__ __launch_bounds__(256) void wcast_t(
    const float* __restrict__ W, unsigned short* __restrict__ Wt,
    int K, int N) {
  __shared__ float tile[32][33];
  int tx = threadIdx.x & 31, ty = threadIdx.x >> 5;   // 32 x 8
  int n0 = blockIdx.x * 32, k0 = blockIdx.y * 32;
  #pragma unroll
  for (int p = 0; p < 4; ++p)
    tile[ty + p * 8][tx] = W[(size_t)(k0 + ty + p * 8) * N + n0 + tx];
  __syncthreads();
  #pragma unroll
  for (int p = 0; p < 4; ++p)
    Wt[(size_t)(n0 + ty + p * 8) * K + k0 + tx] = f2bf(tile[tx][ty + p * 8]);
}

// ---------------------------------------------------------------------------
// K4: bf16 MFMA GEMM (m97 structure).  C = A[M,K] @ W[K,N], Bt = W^T [N][K].
// mode 0: QKV -> bf16 Oq/Ok rows; V transposed to Ovt[bh][d][n]
// mode 1: exact GELU -> bf16 Ob
// mode 2: O0 = res + mod[gate] * acc (fp32)
// ---------------------------------------------------------------------------
__global__ __launch_bounds__(256) void mfma_gemm(
    const unsigned short* __restrict__ A,   // [M][K] bf16
    const unsigned short* __restrict__ Bt,  // [N][K] bf16
    int M, int N, int K,
    float* __restrict__ O0,
    const float* __restrict__ res, const float* __restrict__ mod, int gate_off,
    unsigned short* __restrict__ Ob, unsigned short* __restrict__ Ob2,
    unsigned short* __restrict__ Ob3, int mode) {
  __shared__ unsigned short As[128 * 32];   // row-major, 64 B/row
  __shared__ unsigned short Bs[128 * 32];
  int tid = threadIdx.x;
  int wave = tid >> 6, lane = tid & 63;
  int quad = lane >> 4, l15 = lane & 15;
  int m0 = blockIdx.y * 128, n0 = blockIdx.x * 128;
  int wm = (wave >> 1) * 64, wn = (wave & 1) * 64;

  f4v acc[4][4] = {};

  int srow = lane >> 2;
  int scol = (lane & 3) * 8;

  for (int k0 = 0; k0 < K; k0 += 32) {
    __syncthreads();
    #pragma unroll
    for (int s = 0; s < 2; ++s) {
      int inst = 2 * wave + s;
      const unsigned short* ga =
          A + (size_t)(m0 + inst * 16 + srow) * K + k0 + scol;
      __builtin_amdgcn_global_load_lds(
          (const __attribute__((address_space(1))) unsigned int*)(const void*)ga,
          (__attribute__((address_space(3))) unsigned int*)(void*)(As + inst * 512),
          16, 0, 0);
      const unsigned short* gb =
          Bt + (size_t)(n0 + inst * 16 + srow) * K + k0 + scol;
      __builtin_amdgcn_global_load_lds(
          (const __attribute__((address_space(1))) unsigned int*)(const void*)gb,
          (__attribute__((address_space(3))) unsigned int*)(void*)(Bs + inst * 512),
          16, 0, 0);
    }
    __syncthreads();

    s8v af[4], bf[4];
    #pragma unroll
    for (int i = 0; i < 4; ++i)
      af[i] = *(const s8v*)(As + ((wm + i * 16 + l15) * 32 + quad * 8));
    #pragma unroll
    for (int j = 0; j < 4; ++j)
      bf[j] = *(const s8v*)(Bs + ((wn + j * 16 + l15) * 32 + quad * 8));
    #pragma unroll
    for (int i = 0; i < 4; ++i)
      #pragma unroll
      for (int j = 0; j < 4; ++j)
        acc[i][j] = __builtin_amdgcn_mfma_f32_16x16x32_bf16(
            af[i], bf[j], acc[i][j], 0, 0, 0);
  }

  // epilogue. C/D: col = lane&15 (n), row = quad*4 + reg (m)
  #pragma unroll
  for (int i = 0; i < 4; ++i) {
    int rbase = m0 + wm + i * 16 + quad * 4;
    #pragma unroll
    for (int j = 0; j < 4; ++j) {
      int c = n0 + wn + j * 16 + l15;
      #pragma unroll
      for (int rg = 0; rg < 4; ++rg) {
        int r = rbase + rg;
        float v = acc[i][j][rg];
        if (mode == 0) {
          if (c < 2048) {
            unsigned short* dst = (c < 1024) ? Ob : Ob2;
            dst[(size_t)r * 1024 + (c & 1023)] = f2bf(v);
          } else {
            int d = c & 63, hh = (c >> 6) & 15;
            int bb2 = r >> 11, n = r & 2047;
            Ob3[(((size_t)(bb2 * 16 + hh)) * 64 + d) * NN + n] = f2bf(v);
          }
        } else if (mode == 1) {
          v = 0.5f * v * (1.0f + erff(v * 0.70710678118f));
          Ob[(size_t)r * N + c] = f2bf(v);
        } else {
          int bb2 = r >> 11;
          v = res[(size_t)r * N + c] + mod[bb2 * MODC + gate_off + c] * v;
          O0[(size_t)r * N + c] = v;
        }
      }
    }
  }
}

// ---------------------------------------------------------------------------
// K5: in-place RoPE on bf16 buffer (interleaved pairing), with output scale.
// ---------------------------------------------------------------------------
__global__ __launch_bounds__(256) void rope_bf16(unsigned short* __restrict__ q,
                                                 float scale) {
  int r = blockIdx.x;            // b*N + n
  int n = r % NN;
  int t = threadIdx.x;
  __shared__ float row[CDIM];
  __shared__ float csv[32], snv[32];
  if (t < 32) {
    float invf = powf(10000.0f, -(float)t / 32.0f);
    float sn, cs;
    sincosf((float)n * invf, &sn, &cs);
    csv[t] = cs * scale; snv[t] = sn * scale;
  }
  unsigned short* qr = q + (size_t)r * CDIM;
  ushort4 xv = ((const ushort4*)qr)[t];
  row[t * 4 + 0] = bf2f(xv.x);
  row[t * 4 + 1] = bf2f(xv.y);
  row[t * 4 + 2] = bf2f(xv.z);
  row[t * 4 + 3] = bf2f(xv.w);
  __syncthreads();
  unsigned short o[4];
  #pragma unroll
  for (int q4 = 0; q4 < 4; ++q4) {
    int c = t * 4 + q4;
    int h = c >> 6, d = c & 63;
    int i = d & 31;
    float rh = (d < 32) ? -row[h * 64 + 2 * d + 1] : row[h * 64 + 2 * (d - 32)];
    o[q4] = f2bf(row[c] * csv[i] + rh * snv[i]);
  }
  ((ushort4*)qr)[t] = make_ushort4(o[0], o[1], o[2], o[3]);
}

// ---------------------------------------------------------------------------
// K6: MFMA flash attention.
// Grid: (N/64, B*H), 256 thr = 4 waves x 16 q. 64-key tiles in LDS.
// Q pre-scaled by 1/8 (folded into rope). P via wave-private LDS round-trip.
// ---------------------------------------------------------------------------
__global__ __launch_bounds__(256) void fattn_mfma(
    const unsigned short* __restrict__ qb,   // [B*N][1024] bf16 (scaled)
    const unsigned short* __restrict__ kb,   // [B*N][1024] bf16
    const unsigned short* __restrict__ vtb,  // [B*H][64][2048] bf16
    unsigned short* __restrict__ ob) {       // [B*N][1024] bf16
  int qtile = blockIdx.x;
  int bh = blockIdx.y;
  int b = bh >> 4, h = bh & 15;
  int tid = threadIdx.x;
  int wave = tid >> 6, lane = tid & 63;
  int quad = lane >> 4, l15 = lane & 15;

  __shared__ unsigned short Ks[64 * 72];       // Ks[key][d], row pad 72
  __shared__ unsigned short Vt[64 * 72];       // Vt[d][key], row pad 72
  __shared__ unsigned short Ps[4][16 * 72];    // per-wave P[q][key]

  int n0 = qtile * 64;
  int qrow = n0 + wave * 16 + l15;
  s8v qf[2];
  {
    const unsigned short* qp = qb + (size_t)(b * NN + qrow) * CDIM + h * HDIM;
    qf[0] = *(const s8v*)(qp + quad * 8);
    qf[1] = *(const s8v*)(qp + 32 + quad * 8);
  }

  f4v acc[4] = {};                 // O tiles over d (dt*16+l15)
  float m_i[4], l_i[4];
  #pragma unroll
  for (int r = 0; r < 4; ++r) { m_i[r] = -1e30f; l_i[r] = 0.f; }

  const size_t kbase0 = (size_t)(b * NN) * CDIM + h * HDIM;
  const size_t vbase0 = (size_t)bh * 64 * NN;
  unsigned short* Pw = Ps[wave];

  for (int k0 = 0; k0 < NN; k0 += 64) {
    __syncthreads();
    // stage K tile [64 key][64 d] and V^T tile [64 d][64 key]
    #pragma unroll
    for (int p = 0; p < 2; ++p) {
      int ci = tid + p * 256;          // 0..511
      int row = ci >> 3, cc = (ci & 7) * 8;
      *(s8v*)(Ks + row * 72 + cc) =
          *(const s8v*)(kb + kbase0 + (size_t)(k0 + row) * CDIM + cc);
      *(s8v*)(Vt + row * 72 + cc) =
          *(const s8v*)(vtb + vbase0 + (size_t)row * NN + k0 + cc);
    }
    __syncthreads();

    // ---- S = Q K^T : 4 key tiles x 2 k-steps ----
    f4v s4[4] = {};
    #pragma unroll
    for (int kt = 0; kt < 4; ++kt) {
      s8v kf0 = *(const s8v*)(Ks + (kt * 16 + l15) * 72 + quad * 8);
      s8v kf1 = *(const s8v*)(Ks + (kt * 16 + l15) * 72 + 32 + quad * 8);
      s4[kt] = __builtin_amdgcn_mfma_f32_16x16x32_bf16(qf[0], kf0, s4[kt], 0, 0, 0);
      s4[kt] = __builtin_amdgcn_mfma_f32_16x16x32_bf16(qf[1], kf1, s4[kt], 0, 0, 0);
    }

    // ---- online softmax: rows q = quad*4+r, cols lane&15 + 16*kt ----
    #pragma unroll
    for (int r = 0; r < 4; ++r) {
      float mv = fmaxf(fmaxf(s4[0][r], s4[1][r]), fmaxf(s4[2][r], s4[3][r]));
      #pragma unroll
      for (int msk = 1; msk < 16; msk <<= 1)
        mv = fmaxf(mv, __shfl_xor(mv, msk, 64));
      float mnew = fmaxf(m_i[r], mv);
      float alpha = __expf(m_i[r] - mnew);
      m_i[r] = mnew;
      float ls = 0.f;
      #pragma unroll
      for (int kt = 0; kt < 4; ++kt) {
        float p = __expf(s4[kt][r] - mnew);
        s4[kt][r] = p;
        ls += p;
      }
      #pragma unroll
      for (int msk = 1; msk < 16; msk <<= 1)
        ls += __shfl_xor(ls, msk, 64);
      l_i[r] = l_i[r] * alpha + ls;
      acc[0][r] *= alpha; acc[1][r] *= alpha;
      acc[2][r] *= alpha; acc[3][r] *= alpha;
    }

    // ---- P -> wave-private LDS (C/D layout -> A-operand layout) ----
    #pragma unroll
    for (int kt = 0; kt < 4; ++kt)
      #pragma unroll
      for (int r = 0; r < 4; ++r)
        Pw[(quad * 4 + r) * 72 + kt * 16 + l15] = f2bf(s4[kt][r]);

    s8v pf0 = *(const s8v*)(Pw + l15 * 72 + quad * 8);
    s8v pf1 = *(const s8v*)(Pw + l15 * 72 + 32 + quad * 8);

    // ---- acc += P V : 4 d tiles x 2 k-steps ----
    #pragma unroll
    for (int dt = 0; dt < 4; ++dt) {
      s8v vf0 = *(const s8v*)(Vt + (dt * 16 + l15) * 72 + quad * 8);
      s8v vf1 = *(const s8v*)(Vt + (dt * 16 + l15) * 72 + 32 + quad * 8);
      acc[dt] = __builtin_amdgcn_mfma_f32_16x16x32_bf16(pf0, vf0, acc[dt], 0, 0, 0);
      acc[dt] = __builtin_amdgcn_mfma_f32_16x16x32_bf16(pf1, vf1, acc[dt], 0, 0, 0);
    }
  }

  // ---- epilogue ----
  #pragma unroll
  for (int r = 0; r < 4; ++r) {
    float inv = 1.0f / l_i[r];
    size_t row = (size_t)(b * NN + n0 + wave * 16 + quad * 4 + r);
    unsigned short* op = ob + row * CDIM + h * HDIM;
    #pragma unroll
    for (int dt = 0; dt < 4; ++dt)
      op[dt * 16 + l15] = f2bf(acc[dt][r] * inv);
  }
}

// ---------------------------------------------------------------------------
extern "C" void kernel_launch(void* const* d_in, const int* in_sizes, int n_in,
                              void* d_out, int out_size, void* d_ws, size_t ws_size,
                              hipStream_t stream) {
  const float* x    = (const float*)d_in[0];
  const float* temb = (const float*)d_in[1];
  const float* n1g  = (const float*)d_in[2];
  const float* n1b  = (const float*)d_in[3];
  const float* Wq   = (const float*)d_in[4];
  const float* Wk   = (const float*)d_in[5];
  const float* Wv   = (const float*)d_in[6];
  const float* Wo   = (const float*)d_in[7];
  const float* n2g  = (const float*)d_in[8];
  const float* n2b  = (const float*)d_in[9];
  const float* W1   = (const float*)d_in[10];
  const float* W2   = (const float*)d_in[11];
  const float* adaW = (const float*)d_in[12];
  const float* adab = (const float*)d_in[13];
  float* out = (float*)d_out;

  const size_t TOK = (size_t)BB * NN * CDIM;   // 4,194,304
  float* wsf = (float*)d_ws;
  float* mod = wsf;                                        // 16384 f32
  unsigned short* tokb  = (unsigned short*)(wsf + 16384);  // TOK u16
  unsigned short* qb    = tokb + TOK;
  unsigned short* kb    = qb + TOK;
  unsigned short* vtb   = kb + TOK;
  unsigned short* Wqkvt = vtb + TOK;                       // 3M u16
  unsigned short* Wot   = Wqkvt + 3 * CDIM * CDIM;         // 1M
  unsigned short* W1t   = Wot + CDIM * CDIM;               // 4M
  unsigned short* W2t   = W1t + CDIM * MLPD;               // 4M
  unsigned short* h1b   = W2t + MLPD * CDIM;               // 16.7M u16
  float* x1 = (float*)qb;      // 16 MB alias over qb+kb (dead after fattn)

  const int M = BB * NN;   // 4096

  mod_kernel<<<dim3(MODC / 256, BB), 256, 0, stream>>>(temb, adaW, adab, mod);
  ln_mod_bf16<<<dim3(M), 256, 0, stream>>>(x, n1g, n1b, mod, 0, 1024, tokb);

  wcast_t<<<dim3(32, 32), 256, 0, stream>>>(Wq, Wqkvt, CDIM, CDIM);
  wcast_t<<<dim3(32, 32), 256, 0, stream>>>(Wk, Wqkvt + CDIM * CDIM, CDIM, CDIM);
  wcast_t<<<dim3(32, 32), 256, 0, stream>>>(Wv, Wqkvt + 2 * CDIM * CDIM, CDIM, CDIM);
  wcast_t<<<dim3(32, 32), 256, 0, stream>>>(Wo, Wot, CDIM, CDIM);
  wcast_t<<<dim3(128, 32), 256, 0, stream>>>(W1, W1t, CDIM, MLPD);
  wcast_t<<<dim3(32, 128), 256, 0, stream>>>(W2, W2t, MLPD, CDIM);

  // fused QKV: q,k -> bf16 rows; v -> transposed [bh][d][n] bf16
  mfma_gemm<<<dim3(24, 32), 256, 0, stream>>>(
      tokb, Wqkvt, M, 3 * CDIM, CDIM,
      nullptr, nullptr, nullptr, 0, qb, kb, vtb, 0);

  rope_bf16<<<dim3(M), 256, 0, stream>>>(qb, 0.125f);
  rope_bf16<<<dim3(M), 256, 0, stream>>>(kb, 1.0f);

  fattn_mfma<<<dim3(NN / 64, BB * HEADS), 256, 0, stream>>>(qb, kb, vtb, tokb);

  // x1 = x + gate_msa * (attn @ Wo)
  mfma_gemm<<<dim3(8, 32), 256, 0, stream>>>(
      tokb, Wot, M, CDIM, CDIM,
      x1, x, mod, 2048, nullptr, nullptr, nullptr, 2);

  ln_mod_bf16<<<dim3(M), 256, 0, stream>>>(x1, n2g, n2b, mod, 3072, 4096, tokb);

  // h1 = gelu(xn2 @ W1)
  mfma_gemm<<<dim3(32, 32), 256, 0, stream>>>(
      tokb, W1t, M, MLPD, CDIM,
      nullptr, nullptr, nullptr, 0, h1b, nullptr, nullptr, 1);

  // out = x1 + gate_mlp * (h1 @ W2)
  mfma_gemm<<<dim3(8, 32), 256, 0, stream>>>(
      h1b, W2t, M, CDIM, MLPD,
      out, x1, mod, 5120, nullptr, nullptr, nullptr, 2);
}

// Round 5
// 525.821 us; speedup vs baseline: 11.8456x; 1.1572x over previous
//
#include <hip/hip_runtime.h>
#include <math.h>

#define BB    2
#define NN    2048
#define CDIM  1024
#define HEADS 16
#define HDIM  64
#define MLPD  4096
#define MODC  6144
#define EPSV  1e-5f
#define LOG2E 1.4426950408889634f

typedef __attribute__((ext_vector_type(8))) short s8v;     // 8 bf16 (4 VGPRs)
typedef __attribute__((ext_vector_type(4))) float f4v;     // MFMA C/D

__device__ inline unsigned short f2bf(float f) {
  union { float f; unsigned u; } v; v.f = f;
  unsigned r = v.u + 0x7FFFu + ((v.u >> 16) & 1u);   // RNE
  return (unsigned short)(r >> 16);
}
__device__ inline float bf2f(unsigned short h) {
  union { unsigned u; float f; } v; v.u = ((unsigned)h) << 16;
  return v.f;
}

// ---------------------------------------------------------------------------
// K1: mod = silu(t_emb) @ ada_W + ada_b        (B x 6144)
// ---------------------------------------------------------------------------
__global__ __launch_bounds__(256) void mod_kernel(
    const float* __restrict__ t_emb, const float* __restrict__ ada_W,
    const float* __restrict__ ada_b, float* __restrict__ mod) {
  int b = blockIdx.y;
  int j = blockIdx.x * 256 + threadIdx.x;
  __shared__ float st[CDIM];
  for (int i = threadIdx.x; i < CDIM; i += 256) {
    float v = t_emb[b * CDIM + i];
    st[i] = v / (1.0f + expf(-v));
  }
  __syncthreads();
  float acc = ada_b[j];
  for (int i = 0; i < CDIM; ++i) acc += st[i] * ada_W[(size_t)i * MODC + j];
  mod[b * MODC + j] = acc;
}

// ---------------------------------------------------------------------------
// K2: LN + adaLN modulation, bf16 output
// ---------------------------------------------------------------------------
__device__ inline float wave_sum64(float v) {
  for (int o = 32; o > 0; o >>= 1) v += __shfl_down(v, o, 64);
  return v;
}

__global__ __launch_bounds__(256) void ln_mod_bf16(
    const float* __restrict__ x, const float* __restrict__ g,
    const float* __restrict__ bta, const float* __restrict__ mod,
    int shift_off, int scale_off, unsigned short* __restrict__ out) {
  int r = blockIdx.x;
  int b = r / NN;
  int t = threadIdx.x;
  const float* xr = x + (size_t)r * CDIM;
  float4 xv = ((const float4*)xr)[t];
  float s  = xv.x + xv.y + xv.z + xv.w;
  float s2 = xv.x*xv.x + xv.y*xv.y + xv.z*xv.z + xv.w*xv.w;
  __shared__ float ws1[4], ws2[4];
  float sw = wave_sum64(s), s2w = wave_sum64(s2);
  int lane = t & 63, wid = t >> 6;
  if (lane == 0) { ws1[wid] = sw; ws2[wid] = s2w; }
  __syncthreads();
  float mu  = (ws1[0] + ws1[1] + ws1[2] + ws1[3]) * (1.0f / CDIM);
  float var = (ws2[0] + ws2[1] + ws2[2] + ws2[3]) * (1.0f / CDIM) - mu * mu;
  float rstd = rsqrtf(var + EPSV);
  const float* mods = mod + (size_t)b * MODC;
  float4 gv = ((const float4*)g)[t];
  float4 bv = ((const float4*)bta)[t];
  float4 sc = ((const float4*)(mods + scale_off))[t];
  float4 sh = ((const float4*)(mods + shift_off))[t];
  ushort4 ov;
  ov.x = f2bf(((xv.x - mu) * rstd * gv.x + bv.x) * (1.0f + sc.x) + sh.x);
  ov.y = f2bf(((xv.y - mu) * rstd * gv.y + bv.y) * (1.0f + sc.y) + sh.y);
  ov.z = f2bf(((xv.z - mu) * rstd * gv.z + bv.z) * (1.0f + sc.z) + sh.z);
  ov.w = f2bf(((xv.w - mu) * rstd * gv.w + bv.w) * (1.0f + sc.w) + sh.w);
  ((ushort4*)(out + (size_t)r * CDIM))[t] = ov;
}

// ---------------------------------------------------------------------------
// K3: transpose-cast  W[K][N] fp32  ->  Wt[N][K] bf16   (32x32 tiles)
// ---------------------------------------------------------------------------
__global__ __launch_bounds__(256) void wcast_t(
    const float* __restrict__ W, unsigned short* __restrict__ Wt,
    int K, int N) {
  __shared__ float tile[32][33];
  int tx = threadIdx.x & 31, ty = threadIdx.x >> 5;   // 32 x 8
  int n0 = blockIdx.x * 32, k0 = blockIdx.y * 32;
  #pragma unroll
  for (int p = 0; p < 4; ++p)
    tile[ty + p * 8][tx] = W[(size_t)(k0 + ty + p * 8) * N + n0 + tx];
  __syncthreads();
  #pragma unroll
  for (int p = 0; p < 4; ++p)
    Wt[(size_t)(n0 + ty + p * 8) * K + k0 + tx] = f2bf(tile[tx][ty + p * 8]);
}

// ---------------------------------------------------------------------------
// K4: bf16 MFMA GEMM, 128x128 tile (m97 structure).
// mode 0: QKV -> bf16 rows into Ob/Ob2/Ob3 (each N=1024 slice)
// mode 1: exact GELU -> bf16 Ob
// ---------------------------------------------------------------------------
__global__ __launch_bounds__(256) void mfma_gemm(
    const unsigned short* __restrict__ A,   // [M][K] bf16
    const unsigned short* __restrict__ Bt,  // [N][K] bf16
    int M, int N, int K,
    unsigned short* __restrict__ Ob, unsigned short* __restrict__ Ob2,
    unsigned short* __restrict__ Ob3, int mode) {
  __shared__ unsigned short As[128 * 32];
  __shared__ unsigned short Bs[128 * 32];
  int tid = threadIdx.x;
  int wave = tid >> 6, lane = tid & 63;
  int quad = lane >> 4, l15 = lane & 15;
  int m0 = blockIdx.y * 128, n0 = blockIdx.x * 128;
  int wm = (wave >> 1) * 64, wn = (wave & 1) * 64;

  f4v acc[4][4] = {};
  int srow = lane >> 2;
  int scol = (lane & 3) * 8;

  for (int k0 = 0; k0 < K; k0 += 32) {
    __syncthreads();
    #pragma unroll
    for (int s = 0; s < 2; ++s) {
      int inst = 2 * wave + s;
      const unsigned short* ga =
          A + (size_t)(m0 + inst * 16 + srow) * K + k0 + scol;
      __builtin_amdgcn_global_load_lds(
          (const __attribute__((address_space(1))) unsigned int*)(const void*)ga,
          (__attribute__((address_space(3))) unsigned int*)(void*)(As + inst * 512),
          16, 0, 0);
      const unsigned short* gb =
          Bt + (size_t)(n0 + inst * 16 + srow) * K + k0 + scol;
      __builtin_amdgcn_global_load_lds(
          (const __attribute__((address_space(1))) unsigned int*)(const void*)gb,
          (__attribute__((address_space(3))) unsigned int*)(void*)(Bs + inst * 512),
          16, 0, 0);
    }
    __syncthreads();

    s8v af[4], bf[4];
    #pragma unroll
    for (int i = 0; i < 4; ++i)
      af[i] = *(const s8v*)(As + ((wm + i * 16 + l15) * 32 + quad * 8));
    #pragma unroll
    for (int j = 0; j < 4; ++j)
      bf[j] = *(const s8v*)(Bs + ((wn + j * 16 + l15) * 32 + quad * 8));
    #pragma unroll
    for (int i = 0; i < 4; ++i)
      #pragma unroll
      for (int j = 0; j < 4; ++j)
        acc[i][j] = __builtin_amdgcn_mfma_f32_16x16x32_bf16(
            af[i], bf[j], acc[i][j], 0, 0, 0);
  }

  #pragma unroll
  for (int i = 0; i < 4; ++i) {
    int rbase = m0 + wm + i * 16 + quad * 4;
    #pragma unroll
    for (int j = 0; j < 4; ++j) {
      int c = n0 + wn + j * 16 + l15;
      #pragma unroll
      for (int rg = 0; rg < 4; ++rg) {
        int r = rbase + rg;
        float v = acc[i][j][rg];
        if (mode == 0) {
          unsigned short* dst = (c < 1024) ? Ob : ((c < 2048) ? Ob2 : Ob3);
          dst[(size_t)r * 1024 + (c & 1023)] = f2bf(v);
        } else {
          v = 0.5f * v * (1.0f + erff(v * 0.70710678118f));
          Ob[(size_t)r * N + c] = f2bf(v);
        }
      }
    }
  }
}

// ---------------------------------------------------------------------------
// K4b: bf16 MFMA GEMM, 64x128 tile (2x the blocks for small-grid shapes).
// Epilogue: O0 = res + mod[gate] * acc   (fp32 out)
// ---------------------------------------------------------------------------
__global__ __launch_bounds__(256) void mfma_gemm64(
    const unsigned short* __restrict__ A,   // [M][K] bf16
    const unsigned short* __restrict__ Bt,  // [N][K] bf16
    int M, int N, int K,
    float* __restrict__ O0,
    const float* __restrict__ res, const float* __restrict__ mod,
    int gate_off) {
  __shared__ unsigned short As[64 * 32];
  __shared__ unsigned short Bs[128 * 32];
  int tid = threadIdx.x;
  int wave = tid >> 6, lane = tid & 63;
  int quad = lane >> 4, l15 = lane & 15;
  int m0 = blockIdx.y * 64, n0 = blockIdx.x * 128;
  int wm = (wave >> 1) * 32, wn = (wave & 1) * 64;

  f4v acc[2][4] = {};
  int srow = lane >> 2;
  int scol = (lane & 3) * 8;

  for (int k0 = 0; k0 < K; k0 += 32) {
    __syncthreads();
    {
      const unsigned short* ga =
          A + (size_t)(m0 + wave * 16 + srow) * K + k0 + scol;
      __builtin_amdgcn_global_load_lds(
          (const __attribute__((address_space(1))) unsigned int*)(const void*)ga,
          (__attribute__((address_space(3))) unsigned int*)(void*)(As + wave * 512),
          16, 0, 0);
    }
    #pragma unroll
    for (int s = 0; s < 2; ++s) {
      int inst = 2 * wave + s;
      const unsigned short* gb =
          Bt + (size_t)(n0 + inst * 16 + srow) * K + k0 + scol;
      __builtin_amdgcn_global_load_lds(
          (const __attribute__((address_space(1))) unsigned int*)(const void*)gb,
          (__attribute__((address_space(3))) unsigned int*)(void*)(Bs + inst * 512),
          16, 0, 0);
    }
    __syncthreads();

    s8v af[2], bf[4];
    #pragma unroll
    for (int i = 0; i < 2; ++i)
      af[i] = *(const s8v*)(As + ((wm + i * 16 + l15) * 32 + quad * 8));
    #pragma unroll
    for (int j = 0; j < 4; ++j)
      bf[j] = *(const s8v*)(Bs + ((wn + j * 16 + l15) * 32 + quad * 8));
    #pragma unroll
    for (int i = 0; i < 2; ++i)
      #pragma unroll
      for (int j = 0; j < 4; ++j)
        acc[i][j] = __builtin_amdgcn_mfma_f32_16x16x32_bf16(
            af[i], bf[j], acc[i][j], 0, 0, 0);
  }

  #pragma unroll
  for (int i = 0; i < 2; ++i) {
    int rbase = m0 + wm + i * 16 + quad * 4;
    #pragma unroll
    for (int j = 0; j < 4; ++j) {
      int c = n0 + wn + j * 16 + l15;
      #pragma unroll
      for (int rg = 0; rg < 4; ++rg) {
        int r = rbase + rg;
        int bb2 = r >> 11;   // NN = 2048
        float v = res[(size_t)r * N + c] + mod[bb2 * MODC + gate_off + c] * acc[i][j][rg];
        O0[(size_t)r * N + c] = v;
      }
    }
  }
}

// ---------------------------------------------------------------------------
// K5: in-place RoPE on bf16 buffer (interleaved pairing), with output scale.
// ---------------------------------------------------------------------------
__global__ __launch_bounds__(256) void rope_bf16(unsigned short* __restrict__ q,
                                                 float scale) {
  int r = blockIdx.x;            // b*N + n
  int n = r % NN;
  int t = threadIdx.x;
  __shared__ float row[CDIM];
  __shared__ float csv[32], snv[32];
  if (t < 32) {
    float invf = powf(10000.0f, -(float)t / 32.0f);
    float sn, cs;
    sincosf((float)n * invf, &sn, &cs);
    csv[t] = cs * scale; snv[t] = sn * scale;
  }
  unsigned short* qr = q + (size_t)r * CDIM;
  ushort4 xv = ((const ushort4*)qr)[t];
  row[t * 4 + 0] = bf2f(xv.x);
  row[t * 4 + 1] = bf2f(xv.y);
  row[t * 4 + 2] = bf2f(xv.z);
  row[t * 4 + 3] = bf2f(xv.w);
  __syncthreads();
  unsigned short o[4];
  #pragma unroll
  for (int q4 = 0; q4 < 4; ++q4) {
    int c = t * 4 + q4;
    int h = c >> 6, d = c & 63;
    int i = d & 31;
    float rh = (d < 32) ? -row[h * 64 + 2 * d + 1] : row[h * 64 + 2 * (d - 32)];
    o[q4] = f2bf(row[c] * csv[i] + rh * snv[i]);
  }
  ((ushort4*)qr)[t] = make_ushort4(o[0], o[1], o[2], o[3]);
}

// ---------------------------------------------------------------------------
// K5b: V transpose  v[B*N][1024] bf16 -> vtb[B*H][64][2048] bf16
// u32 LDS tile (bf16 pairs), coalesced reads and writes.
// ---------------------------------------------------------------------------
__global__ __launch_bounds__(256) void vtrans(
    const unsigned int* __restrict__ v,     // [B*N][512] u32
    unsigned short* __restrict__ vtb) {
  int nb = blockIdx.x;      // n0 = nb*64
  int bh = blockIdx.y;      // b*16 + h
  int b = bh >> 4, h = bh & 15;
  __shared__ unsigned int Ts[64][33];
  int n0 = nb * 64;
  int tid = threadIdx.x;
  int col = tid & 31, r0 = tid >> 5;        // 8 rows per pass
  #pragma unroll
  for (int p = 0; p < 8; ++p) {
    int row = r0 + p * 8;
    Ts[row][col] = v[(size_t)(b * NN + n0 + row) * 512 + h * 32 + col];
  }
  __syncthreads();
  int np = tid & 31, d0 = tid >> 5;         // thread covers d = d0*8 .. +7
  #pragma unroll
  for (int i = 0; i < 8; ++i) {
    int d = d0 * 8 + i;
    unsigned int lo = Ts[np * 2][d >> 1];
    unsigned int hi = Ts[np * 2 + 1][d >> 1];
    unsigned int a  = (d & 1) ? (lo >> 16) : (lo & 0xffffu);
    unsigned int c2 = (d & 1) ? (hi >> 16) : (hi & 0xffffu);
    ((unsigned int*)(vtb + ((size_t)bh * 64 + d) * NN + n0))[np] =
        a | (c2 << 16);
  }
}

// ---------------------------------------------------------------------------
// K6: MFMA flash attention, register-pipelined K/V staging.
// Q pre-scaled by (1/8)*log2(e) in rope -> softmax uses exp2.
// ---------------------------------------------------------------------------
__global__ __launch_bounds__(256) void fattn_mfma(
    const unsigned short* __restrict__ qb,   // [B*N][1024] (scaled)
    const unsigned short* __restrict__ kb,   // [B*N][1024]
    const unsigned short* __restrict__ vtb,  // [B*H][64][2048]
    unsigned short* __restrict__ ob) {       // [B*N][1024]
  int qtile = blockIdx.x;
  int bh = blockIdx.y;
  int b = bh >> 4, h = bh & 15;
  int tid = threadIdx.x;
  int wave = tid >> 6, lane = tid & 63;
  int quad = lane >> 4, l15 = lane & 15;

  __shared__ unsigned short Ks[64 * 72];       // Ks[key][d]
  __shared__ unsigned short Vt[64 * 72];       // Vt[d][key]
  __shared__ unsigned short Ps[4][16 * 72];    // per-wave P[q][key]

  int n0 = qtile * 64;
  int qrow = n0 + wave * 16 + l15;
  s8v qf[2];
  {
    const unsigned short* qp = qb + (size_t)(b * NN + qrow) * CDIM + h * HDIM;
    qf[0] = *(const s8v*)(qp + quad * 8);
    qf[1] = *(const s8v*)(qp + 32 + quad * 8);
  }

  f4v acc[4] = {};
  float m_i[4], l_i[4];
  #pragma unroll
  for (int r = 0; r < 4; ++r) { m_i[r] = -1e30f; l_i[r] = 0.f; }

  const unsigned short* kg = kb + (size_t)(b * NN) * CDIM + h * HDIM;
  const unsigned short* vg = vtb + (size_t)bh * 64 * NN;
  unsigned short* Pw = Ps[wave];

  // staging chunks: this thread owns (r0,c0) and (r0+32,c0)
  int r0 = tid >> 3, c0 = (tid & 7) * 8;

  // prefetch tile 0 into registers
  s8v rk0 = *(const s8v*)(kg + (size_t)r0 * CDIM + c0);
  s8v rk1 = *(const s8v*)(kg + (size_t)(r0 + 32) * CDIM + c0);
  s8v rv0 = *(const s8v*)(vg + (size_t)r0 * NN + c0);
  s8v rv1 = *(const s8v*)(vg + (size_t)(r0 + 32) * NN + c0);

  for (int t = 0; t < NN / 64; ++t) {
    __syncthreads();                     // prev tile's LDS reads done
    *(s8v*)(Ks + r0 * 72 + c0) = rk0;
    *(s8v*)(Ks + (r0 + 32) * 72 + c0) = rk1;
    *(s8v*)(Vt + r0 * 72 + c0) = rv0;
    *(s8v*)(Vt + (r0 + 32) * 72 + c0) = rv1;
    if (t + 1 < NN / 64) {               // prefetch next tile (lands during compute)
      int k0n = (t + 1) * 64;
      rk0 = *(const s8v*)(kg + (size_t)(k0n + r0) * CDIM + c0);
      rk1 = *(const s8v*)(kg + (size_t)(k0n + r0 + 32) * CDIM + c0);
      rv0 = *(const s8v*)(vg + (size_t)r0 * NN + k0n + c0);
      rv1 = *(const s8v*)(vg + (size_t)(r0 + 32) * NN + k0n + c0);
    }
    __syncthreads();                     // staging visible

    // ---- S = Q K^T (units of log2e) ----
    f4v s4[4] = {};
    #pragma unroll
    for (int kt = 0; kt < 4; ++kt) {
      s8v kf0 = *(const s8v*)(Ks + (kt * 16 + l15) * 72 + quad * 8);
      s8v kf1 = *(const s8v*)(Ks + (kt * 16 + l15) * 72 + 32 + quad * 8);
      s4[kt] = __builtin_amdgcn_mfma_f32_16x16x32_bf16(qf[0], kf0, s4[kt], 0, 0, 0);
      s4[kt] = __builtin_amdgcn_mfma_f32_16x16x32_bf16(qf[1], kf1, s4[kt], 0, 0, 0);
    }

    // ---- online softmax (exp2; l-sum kept as per-lane partial) ----
    #pragma unroll
    for (int r = 0; r < 4; ++r) {
      float mv = fmaxf(fmaxf(s4[0][r], s4[1][r]), fmaxf(s4[2][r], s4[3][r]));
      #pragma unroll
      for (int msk = 1; msk < 16; msk <<= 1)
        mv = fmaxf(mv, __shfl_xor(mv, msk, 64));
      float mnew = fmaxf(m_i[r], mv);
      float alpha = __builtin_amdgcn_exp2f(m_i[r] - mnew);
      m_i[r] = mnew;
      float ls = 0.f;
      #pragma unroll
      for (int kt = 0; kt < 4; ++kt) {
        float p = __builtin_amdgcn_exp2f(s4[kt][r] - mnew);
        s4[kt][r] = p;
        ls += p;
      }
      l_i[r] = l_i[r] * alpha + ls;
      acc[0][r] *= alpha; acc[1][r] *= alpha;
      acc[2][r] *= alpha; acc[3][r] *= alpha;
    }

    // ---- P -> wave-private LDS (truncating bf16 convert) ----
    #pragma unroll
    for (int kt = 0; kt < 4; ++kt)
      #pragma unroll
      for (int r = 0; r < 4; ++r)
        Pw[(quad * 4 + r) * 72 + kt * 16 + l15] =
            (unsigned short)(__float_as_uint(s4[kt][r]) >> 16);

    s8v pf0 = *(const s8v*)(Pw + l15 * 72 + quad * 8);
    s8v pf1 = *(const s8v*)(Pw + l15 * 72 + 32 + quad * 8);

    // ---- acc += P V ----
    #pragma unroll
    for (int dt = 0; dt < 4; ++dt) {
      s8v vf0 = *(const s8v*)(Vt + (dt * 16 + l15) * 72 + quad * 8);
      s8v vf1 = *(const s8v*)(Vt + (dt * 16 + l15) * 72 + 32 + quad * 8);
      acc[dt] = __builtin_amdgcn_mfma_f32_16x16x32_bf16(pf0, vf0, acc[dt], 0, 0, 0);
      acc[dt] = __builtin_amdgcn_mfma_f32_16x16x32_bf16(pf1, vf1, acc[dt], 0, 0, 0);
    }
  }

  // ---- epilogue: finish l reduction, normalize, store ----
  #pragma unroll
  for (int r = 0; r < 4; ++r) {
    float l = l_i[r];
    #pragma unroll
    for (int msk = 1; msk < 16; msk <<= 1)
      l += __shfl_xor(l, msk, 64);
    float inv = 1.0f / l;
    size_t row = (size_t)(b * NN + n0 + wave * 16 + quad * 4 + r);
    unsigned short* op = ob + row * CDIM + h * HDIM;
    #pragma unroll
    for (int dt = 0; dt < 4; ++dt)
      op[dt * 16 + l15] = f2bf(acc[dt][r] * inv);
  }
}

// ---------------------------------------------------------------------------
extern "C" void kernel_launch(void* const* d_in, const int* in_sizes, int n_in,
                              void* d_out, int out_size, void* d_ws, size_t ws_size,
                              hipStream_t stream) {
  const float* x    = (const float*)d_in[0];
  const float* temb = (const float*)d_in[1];
  const float* n1g  = (const float*)d_in[2];
  const float* n1b  = (const float*)d_in[3];
  const float* Wq   = (const float*)d_in[4];
  const float* Wk   = (const float*)d_in[5];
  const float* Wv   = (const float*)d_in[6];
  const float* Wo   = (const float*)d_in[7];
  const float* n2g  = (const float*)d_in[8];
  const float* n2b  = (const float*)d_in[9];
  const float* W1   = (const float*)d_in[10];
  const float* W2   = (const float*)d_in[11];
  const float* adaW = (const float*)d_in[12];
  const float* adab = (const float*)d_in[13];
  float* out = (float*)d_out;

  const size_t TOK = (size_t)BB * NN * CDIM;   // 4,194,304
  float* wsf = (float*)d_ws;
  float* mod = wsf;                                        // 16384 f32
  unsigned short* tokb  = (unsigned short*)(wsf + 16384);  // TOK u16
  unsigned short* qb    = tokb + TOK;
  unsigned short* kb    = qb + TOK;
  unsigned short* vtb   = kb + TOK;
  unsigned short* Wqkvt = vtb + TOK;                       // 3M u16
  unsigned short* Wot   = Wqkvt + 3 * CDIM * CDIM;         // 1M
  unsigned short* W1t   = Wot + CDIM * CDIM;               // 4M
  unsigned short* W2t   = W1t + CDIM * MLPD;               // 4M
  unsigned short* h1b   = W2t + MLPD * CDIM;               // 16.7M u16
  unsigned short* vrow  = h1b;          // staging alias (dead before W1 GEMM)
  float* x1 = (float*)qb;               // fp32 alias over qb+kb (dead after fattn)

  const int M = BB * NN;   // 4096

  mod_kernel<<<dim3(MODC / 256, BB), 256, 0, stream>>>(temb, adaW, adab, mod);
  ln_mod_bf16<<<dim3(M), 256, 0, stream>>>(x, n1g, n1b, mod, 0, 1024, tokb);

  wcast_t<<<dim3(32, 32), 256, 0, stream>>>(Wq, Wqkvt, CDIM, CDIM);
  wcast_t<<<dim3(32, 32), 256, 0, stream>>>(Wk, Wqkvt + CDIM * CDIM, CDIM, CDIM);
  wcast_t<<<dim3(32, 32), 256, 0, stream>>>(Wv, Wqkvt + 2 * CDIM * CDIM, CDIM, CDIM);
  wcast_t<<<dim3(32, 32), 256, 0, stream>>>(Wo, Wot, CDIM, CDIM);
  wcast_t<<<dim3(128, 32), 256, 0, stream>>>(W1, W1t, CDIM, MLPD);
  wcast_t<<<dim3(32, 128), 256, 0, stream>>>(W2, W2t, MLPD, CDIM);

  // fused QKV -> q,k,v row-major bf16
  mfma_gemm<<<dim3(24, 32), 256, 0, stream>>>(
      tokb, Wqkvt, M, 3 * CDIM, CDIM, qb, kb, vrow, 0);

  rope_bf16<<<dim3(M), 256, 0, stream>>>(qb, 0.125f * LOG2E);
  rope_bf16<<<dim3(M), 256, 0, stream>>>(kb, 1.0f);

  vtrans<<<dim3(NN / 64, BB * HEADS), 256, 0, stream>>>(
      (const unsigned int*)vrow, vtb);

  fattn_mfma<<<dim3(NN / 64, BB * HEADS), 256, 0, stream>>>(qb, kb, vtb, tokb);

  // x1 = x + gate_msa * (attn @ Wo)     (512 blocks)
  mfma_gemm64<<<dim3(CDIM / 128, M / 64), 256, 0, stream>>>(
      tokb, Wot, M, CDIM, CDIM, x1, x, mod, 2048);

  ln_mod_bf16<<<dim3(M), 256, 0, stream>>>(x1, n2g, n2b, mod, 3072, 4096, tokb);

  // h1 = gelu(xn2 @ W1)
  mfma_gemm<<<dim3(MLPD / 128, M / 128), 256, 0, stream>>>(
      tokb, W1t, M, MLPD, CDIM, h1b, nullptr, nullptr, 1);

  // out = x1 + gate_mlp * (h1 @ W2)     (512 blocks)
  mfma_gemm64<<<dim3(CDIM / 128, M / 64), 256, 0, stream>>>(
      h1b, W2t, M, CDIM, MLPD, out, x1, mod, 5120);
}